// Round 2
// baseline (676.850 us; speedup 1.0000x reference)
//
#include <hip/hip_runtime.h>
#include <stdint.h>

// Problem constants (reference: N=8192, IN_DIM=512, LDIM=256)
#define NN 8192
#define KDIM 512
#define LDIM 256

typedef short bf16x8 __attribute__((ext_vector_type(8)));
typedef short short8 __attribute__((ext_vector_type(8)));
typedef float f32x4 __attribute__((ext_vector_type(4)));
typedef unsigned short u16x4 __attribute__((ext_vector_type(4)));

// fp32 -> bf16 with round-to-nearest-even
__device__ __forceinline__ unsigned short f2bf(float f) {
  unsigned int u = __float_as_uint(f);
  u = (u + 0x7fffu + ((u >> 16) & 1u)) >> 16;
  return (unsigned short)u;
}
__device__ __forceinline__ float bf2f(unsigned short s) {
  return __uint_as_float(((unsigned int)s) << 16);
}

// async global->LDS, 16B per lane; LDS dest = wave-uniform base + lane*16
__device__ __forceinline__ void async_ld16(const unsigned short* g, void* l) {
  __builtin_amdgcn_global_load_lds(
      (const __attribute__((address_space(1))) unsigned int*)g,
      (__attribute__((address_space(3))) unsigned int*)l, 16, 0, 0);
}

// Cast x [8192x512] and proj_w [256x512] to bf16. 4 floats/thread.
__global__ __launch_bounds__(256) void cast_kernel(
    const float* __restrict__ x, const float* __restrict__ pw,
    unsigned short* __restrict__ xb, unsigned short* __restrict__ pwb) {
  const int i = blockIdx.x * 256 + threadIdx.x;  // float4 index
  float4 v = ((const float4*)x)[i];
  u16x4 o;
  o[0] = (short)f2bf(v.x); o[1] = (short)f2bf(v.y);
  o[2] = (short)f2bf(v.z); o[3] = (short)f2bf(v.w);
  ((u16x4*)xb)[i] = o;
  if (i < (LDIM * KDIM) / 4) {
    float4 w = ((const float4*)pw)[i];
    u16x4 ow;
    ow[0] = (short)f2bf(w.x); ow[1] = (short)f2bf(w.y);
    ow[2] = (short)f2bf(w.z); ow[3] = (short)f2bf(w.w);
    ((u16x4*)pwb)[i] = ow;
  }
}

// Row-normalize x_hat, emit A = bf16(xn*w), B = bf16(xn). One block per row.
__global__ __launch_bounds__(256) void norm_kernel(
    const float* __restrict__ xh, const float* __restrict__ w,
    unsigned short* __restrict__ Ab, unsigned short* __restrict__ Bb) {
  const int row = blockIdx.x;
  const int d = threadIdx.x;
  const float v = xh[row * LDIM + d];
  float ss = v * v;
#pragma unroll
  for (int m = 1; m < 64; m <<= 1) ss += __shfl_xor(ss, m);
  __shared__ float s4[4];
  if ((d & 63) == 0) s4[d >> 6] = ss;
  __syncthreads();
  const float tot = s4[0] + s4[1] + s4[2] + s4[3];
  const float inv = 1.0f / sqrtf(tot);
  const float xn = v * inv;
  Bb[row * LDIM + d] = f2bf(xn);
  Ab[row * LDIM + d] = f2bf(xn * w[d]);
}

// D = A * B^T, A [M,K] bf16 K-major, B [N,K] bf16 K-major.
// 128x128 tile, 256 threads = 4 waves (2x2), each wave 64x64 via 4x4 grid of
// v_mfma_f32_16x16x32_bf16.
//
// MODE 0 [GEMM1]: LDS-staged double-buffered K-loop (proven path), store D
//   (fp32) to C with the classic layout (col=l16, row=quad*4+r).
//
// MODE 1/2 [GEMM2]: A,B are 4 MB each (L2/L3-resident) -> NO LDS staging,
//   fragments loaded straight from global; NO barriers in the K-loop.
//   Operands SWAPPED in the MFMA: mfma(bv, av) computes the transposed
//   fragment layout, so each lane holds D[row = mt*16+l16]
//   [col = nt*16+quad*4 + r] -- 4 contiguous columns of one row per reg
//   quad. Epilogue reads adj as per-lane float4 and stores bf16x4 (8B)
//   directly from accumulators: no LDS transpose, no epilogue barriers.
//   LDS = 1 KB rowsum scratch -> occupancy VGPR-capped (~4 waves/SIMD).
// MODE 1: t = adj*exp(-D) -> bf16 to T; rowsum atomics.
// MODE 2: t = adj*exp(-D) -> fp32 to C; rowsum atomics.
template <int K, int MODE>
__global__ __launch_bounds__(256) void gemm_bt(
    const unsigned short* __restrict__ A,
    const unsigned short* __restrict__ B,
    float* __restrict__ C,
    unsigned short* __restrict__ T,
    const float* __restrict__ adj,
    float* __restrict__ rowsum,
    int ldC) {
  const int tid = threadIdx.x;
  const int wave = tid >> 6;
  const int lane = tid & 63;
  const int quad = lane >> 4;
  const int l16 = lane & 15;
  const int wm = wave >> 1;
  const int wn = wave & 1;

  const size_t row0 = (size_t)blockIdx.y * 128;
  const size_t col0 = (size_t)blockIdx.x * 128;

  f32x4 acc[4][4];
#pragma unroll
  for (int i = 0; i < 4; ++i)
#pragma unroll
    for (int j = 0; j < 4; ++j) acc[i][j] = (f32x4)(0.0f);

  if constexpr (MODE == 0) {
    // ---- staged, double-buffered path (GEMM1) ----
    __shared__ alignas(16) char sm[32768];
    // staging map: chunk c = wave*128 + lane covers LDS bytes [c*16, c*16+16)
    // within a buffer; tile layout [128 rows][32 k] bf16 => row m = c>>2,
    // k offset = (c&3)*8.
    const int c0 = wave * 128 + lane;
    const int mA = c0 >> 2;
    const int kA = (c0 & 3) * 8;
    const unsigned short* Ag = A + (row0 + mA) * (size_t)K + kA;
    const unsigned short* Bg = B + (col0 + mA) * (size_t)K + kA;
    char* const a0d = sm + wave * 2048;
    char* const b0d = sm + 8192 + wave * 2048;
    char* const a1d = sm + 16384 + wave * 2048;
    char* const b1d = sm + 24576 + wave * 2048;

    auto stage = [&](char* Ad, char* Bd, int k0) {
      async_ld16(Ag + k0, Ad);
      async_ld16(Ag + 16 * (size_t)K + k0, Ad + 1024);
      async_ld16(Bg + k0, Bd);
      async_ld16(Bg + 16 * (size_t)K + k0, Bd + 1024);
    };
    auto compute = [&](const char* Ab_, const char* Bb_) {
      bf16x8 av[4], bv[4];
#pragma unroll
      for (int mt = 0; mt < 4; ++mt)
        av[mt] = *(const bf16x8*)(Ab_ + (wm * 64 + mt * 16 + l16) * 64 + quad * 16);
#pragma unroll
      for (int nt = 0; nt < 4; ++nt)
        bv[nt] = *(const bf16x8*)(Bb_ + (wn * 64 + nt * 16 + l16) * 64 + quad * 16);
#pragma unroll
      for (int mt = 0; mt < 4; ++mt)
#pragma unroll
        for (int nt = 0; nt < 4; ++nt)
          acc[mt][nt] = __builtin_amdgcn_mfma_f32_16x16x32_bf16(
              av[mt], bv[nt], acc[mt][nt], 0, 0, 0);
    };

    stage(a0d, b0d, 0);
    __syncthreads();
    for (int k0 = 0; k0 < K; k0 += 64) {
      if (k0 + 32 < K) stage(a1d, b1d, k0 + 32);
      compute(sm, sm + 8192);
      __syncthreads();
      if (k0 + 64 < K) stage(a0d, b0d, k0 + 64);
      if (k0 + 32 < K) compute(sm + 16384, sm + 24576);
      __syncthreads();
    }

#pragma unroll
    for (int mt = 0; mt < 4; ++mt)
#pragma unroll
      for (int nt = 0; nt < 4; ++nt)
#pragma unroll
        for (int r = 0; r < 4; ++r) {
          // classic C/D layout: col = l16, row = quad*4 + r [m89/m91]
          size_t gr = row0 + wm * 64 + mt * 16 + quad * 4 + r;
          size_t gc = col0 + wn * 64 + nt * 16 + l16;
          C[gr * (size_t)ldC + gc] = acc[mt][nt][r];
        }
  } else {
    // ---- barrier-free direct-global path (GEMM2) ----
    __shared__ float rs[2][128];
    const unsigned short* Arow = A + (row0 + wm * 64 + l16) * (size_t)K + quad * 8;
    const unsigned short* Brow = B + (col0 + wn * 64 + l16) * (size_t)K + quad * 8;

#pragma unroll
    for (int k0 = 0; k0 < K; k0 += 32) {
      bf16x8 av[4], bv[4];
#pragma unroll
      for (int mt = 0; mt < 4; ++mt)
        av[mt] = *(const bf16x8*)(Arow + (size_t)mt * 16 * K + k0);
#pragma unroll
      for (int nt = 0; nt < 4; ++nt)
        bv[nt] = *(const bf16x8*)(Brow + (size_t)nt * 16 * K + k0);
#pragma unroll
      for (int mt = 0; mt < 4; ++mt)
#pragma unroll
        for (int nt = 0; nt < 4; ++nt)
          // SWAPPED: computes transposed fragment layout ->
          // lane holds D[mt*16+l16][nt*16+quad*4 + r]
          acc[mt][nt] = __builtin_amdgcn_mfma_f32_16x16x32_bf16(
              bv[nt], av[mt], acc[mt][nt], 0, 0, 0);
    }

    float part[4] = {0.0f, 0.0f, 0.0f, 0.0f};
#pragma unroll
    for (int mt = 0; mt < 4; ++mt) {
      const size_t gr = row0 + wm * 64 + mt * 16 + l16;
      const float* arow = adj + gr * NN;
#pragma unroll
      for (int nt = 0; nt < 4; ++nt) {
        const size_t gc = col0 + wn * 64 + nt * 16 + quad * 4;
        float4 a4 = *(const float4*)(arow + gc);
        f32x4 d = acc[mt][nt];
        float t0 = a4.x * __expf(-d[0]);
        float t1 = a4.y * __expf(-d[1]);
        float t2 = a4.z * __expf(-d[2]);
        float t3 = a4.w * __expf(-d[3]);
        if constexpr (MODE == 1) {
          u16x4 p;
          p[0] = (short)f2bf(t0); p[1] = (short)f2bf(t1);
          p[2] = (short)f2bf(t2); p[3] = (short)f2bf(t3);
          // rowsum of the *rounded* t: self-consistent with scale pass
          part[mt] += bf2f(p[0]) + bf2f(p[1]) + bf2f(p[2]) + bf2f(p[3]);
          *(u16x4*)(T + gr * NN + gc) = p;
        } else {
          part[mt] += t0 + t1 + t2 + t3;
          float4 o; o.x = t0; o.y = t1; o.z = t2; o.w = t3;
          *(float4*)(C + gr * NN + gc) = o;
        }
      }
    }
    // reduce across the 4 quads holding the same row (lane bits 4-5)
#pragma unroll
    for (int mt = 0; mt < 4; ++mt) {
      part[mt] += __shfl_xor(part[mt], 16);
      part[mt] += __shfl_xor(part[mt], 32);
    }
    if (quad == 0) {
#pragma unroll
      for (int mt = 0; mt < 4; ++mt)
        rs[wn][wm * 64 + mt * 16 + l16] = part[mt];
    }
    __syncthreads();
    if (tid < 128) atomicAdd(&rowsum[row0 + tid], rs[0][tid] + rs[1][tid]);
  }
}

// out = bf16(t) * (1/rowsum[row]) + 1e-10; 16 elems/thread:
// read 2x short8 (32B), write 4x float4 (64B)
__global__ __launch_bounds__(256) void scale_bf16_kernel(
    const unsigned short* __restrict__ T, const float* __restrict__ rowsum,
    float* __restrict__ out) {
  const size_t i = (size_t)blockIdx.x * 256 + threadIdx.x;  // 16-elem chunk
  const int row = (int)(i >> 9);  // 512 chunks per row
  const float inv = 1.0f / rowsum[row];
  short8 t0 = ((const short8*)T)[i * 2];
  short8 t1 = ((const short8*)T)[i * 2 + 1];
  float4 o0, o1, o2, o3;
  o0.x = bf2f((unsigned short)t0[0]) * inv + 1e-10f;
  o0.y = bf2f((unsigned short)t0[1]) * inv + 1e-10f;
  o0.z = bf2f((unsigned short)t0[2]) * inv + 1e-10f;
  o0.w = bf2f((unsigned short)t0[3]) * inv + 1e-10f;
  o1.x = bf2f((unsigned short)t0[4]) * inv + 1e-10f;
  o1.y = bf2f((unsigned short)t0[5]) * inv + 1e-10f;
  o1.z = bf2f((unsigned short)t0[6]) * inv + 1e-10f;
  o1.w = bf2f((unsigned short)t0[7]) * inv + 1e-10f;
  o2.x = bf2f((unsigned short)t1[0]) * inv + 1e-10f;
  o2.y = bf2f((unsigned short)t1[1]) * inv + 1e-10f;
  o2.z = bf2f((unsigned short)t1[2]) * inv + 1e-10f;
  o2.w = bf2f((unsigned short)t1[3]) * inv + 1e-10f;
  o3.x = bf2f((unsigned short)t1[4]) * inv + 1e-10f;
  o3.y = bf2f((unsigned short)t1[5]) * inv + 1e-10f;
  o3.z = bf2f((unsigned short)t1[6]) * inv + 1e-10f;
  o3.w = bf2f((unsigned short)t1[7]) * inv + 1e-10f;
  float4* dst = (float4*)(out + i * 16);
  dst[0] = o0; dst[1] = o1; dst[2] = o2; dst[3] = o3;
}

// Fallback: in-place out = t / rowsum[row] + 1e-10 (t fp32 already in out)
__global__ __launch_bounds__(256) void scale_f32_kernel(
    float* __restrict__ t, const float* __restrict__ rowsum) {
  const size_t i = (size_t)blockIdx.x * 256 + threadIdx.x;
  const int row = (int)(i >> 11);
  float4 v = ((float4*)t)[i];
  const float inv = 1.0f / rowsum[row];
  v.x = v.x * inv + 1e-10f;
  v.y = v.y * inv + 1e-10f;
  v.z = v.z * inv + 1e-10f;
  v.w = v.w * inv + 1e-10f;
  ((float4*)t)[i] = v;
}

extern "C" void kernel_launch(void* const* d_in, const int* in_sizes, int n_in,
                              void* d_out, int out_size, void* d_ws, size_t ws_size,
                              hipStream_t stream) {
  (void)in_sizes; (void)n_in; (void)out_size;
  const float* x   = (const float*)d_in[0];  // [8192,512]
  const float* adj = (const float*)d_in[1];  // [8192,8192]
  const float* pw  = (const float*)d_in[2];  // [256,512]
  const float* lw  = (const float*)d_in[3];  // [256]
  float* out = (float*)d_out;                // [8192,8192]
  char* ws = (char*)d_ws;

  // ws layout (bytes)
  unsigned short* xb   = (unsigned short*)(ws);              // 8 MB
  unsigned short* pwb  = (unsigned short*)(ws + 8388608);    // 256 KB
  float*          xhat = (float*)(ws + 8650752);             // 8 MB
  unsigned short* Ab   = (unsigned short*)(ws + 17039360);   // 4 MB
  unsigned short* Bb   = (unsigned short*)(ws + 21233664);   // 4 MB
  float*          rsum = (float*)(ws + 25427968);            // 32 KB
  unsigned short* Tbuf = (unsigned short*)(ws + 25460736);   // 128 MB (if fits)
  const bool big_ws = ws_size >= 25460736ull + (size_t)NN * NN * 2ull;

  // 1) cast inputs to bf16 (4 floats/thread)
  cast_kernel<<<(NN * KDIM) / (256 * 4), 256, 0, stream>>>(x, pw, xb, pwb);
  // 2) x_hat = x @ proj_w^T : M=8192, N=256, K=512
  gemm_bt<KDIM, 0><<<dim3(2, 64), 256, 0, stream>>>(xb, pwb, xhat, nullptr, nullptr, nullptr, LDIM);
  // 3) normalize rows; A = xn*w, B = xn (bf16)
  norm_kernel<<<NN, 256, 0, stream>>>(xhat, lw, Ab, Bb);
  // 4) t = adj * exp(-(A@B^T)), plus rowsums
  hipMemsetAsync(rsum, 0, NN * sizeof(float), stream);
  if (big_ws) {
    gemm_bt<LDIM, 1><<<dim3(64, 64), 256, 0, stream>>>(Ab, Bb, nullptr, Tbuf, adj, rsum, NN);
    // 5) out = t / rowsum + eps (16 elems/thread)
    scale_bf16_kernel<<<(NN * NN) / (16 * 256), 256, 0, stream>>>(Tbuf, rsum, out);
  } else {
    gemm_bt<LDIM, 2><<<dim3(64, 64), 256, 0, stream>>>(Ab, Bb, out, nullptr, adj, rsum, NN);
    scale_f32_kernel<<<(NN / 4) * (NN / 256), 256, 0, stream>>>(out, rsum);
  }
}

// Round 3
// 601.651 us; speedup vs baseline: 1.1250x; 1.1250x over previous
//
#include <hip/hip_runtime.h>
#include <stdint.h>

// Problem constants (reference: N=8192, IN_DIM=512, LDIM=256)
#define NN 8192
#define KDIM 512
#define LDIM 256

typedef short bf16x8 __attribute__((ext_vector_type(8)));
typedef short short8 __attribute__((ext_vector_type(8)));
typedef float f32x4 __attribute__((ext_vector_type(4)));
typedef unsigned short u16x4 __attribute__((ext_vector_type(4)));

// fp32 -> bf16 with round-to-nearest-even
__device__ __forceinline__ unsigned short f2bf(float f) {
  unsigned int u = __float_as_uint(f);
  u = (u + 0x7fffu + ((u >> 16) & 1u)) >> 16;
  return (unsigned short)u;
}
__device__ __forceinline__ float bf2f(unsigned short s) {
  return __uint_as_float(((unsigned int)s) << 16);
}

// async global->LDS, 16B per lane; LDS dest = wave-uniform base + lane*16
__device__ __forceinline__ void async_ld16(const unsigned short* g, void* l) {
  __builtin_amdgcn_global_load_lds(
      (const __attribute__((address_space(1))) unsigned int*)g,
      (__attribute__((address_space(3))) unsigned int*)l, 16, 0, 0);
}

// Cast x [8192x512] and proj_w [256x512] to bf16. 4 floats/thread.
__global__ __launch_bounds__(256) void cast_kernel(
    const float* __restrict__ x, const float* __restrict__ pw,
    unsigned short* __restrict__ xb, unsigned short* __restrict__ pwb) {
  const int i = blockIdx.x * 256 + threadIdx.x;  // float4 index
  float4 v = ((const float4*)x)[i];
  u16x4 o;
  o[0] = (short)f2bf(v.x); o[1] = (short)f2bf(v.y);
  o[2] = (short)f2bf(v.z); o[3] = (short)f2bf(v.w);
  ((u16x4*)xb)[i] = o;
  if (i < (LDIM * KDIM) / 4) {
    float4 w = ((const float4*)pw)[i];
    u16x4 ow;
    ow[0] = (short)f2bf(w.x); ow[1] = (short)f2bf(w.y);
    ow[2] = (short)f2bf(w.z); ow[3] = (short)f2bf(w.w);
    ((u16x4*)pwb)[i] = ow;
  }
}

// Row-normalize x_hat, emit A = bf16(xn*w), B = bf16(xn). One block per row.
__global__ __launch_bounds__(256) void norm_kernel(
    const float* __restrict__ xh, const float* __restrict__ w,
    unsigned short* __restrict__ Ab, unsigned short* __restrict__ Bb) {
  const int row = blockIdx.x;
  const int d = threadIdx.x;
  const float v = xh[row * LDIM + d];
  float ss = v * v;
#pragma unroll
  for (int m = 1; m < 64; m <<= 1) ss += __shfl_xor(ss, m);
  __shared__ float s4[4];
  if ((d & 63) == 0) s4[d >> 6] = ss;
  __syncthreads();
  const float tot = s4[0] + s4[1] + s4[2] + s4[3];
  const float inv = 1.0f / sqrtf(tot);
  const float xn = v * inv;
  Bb[row * LDIM + d] = f2bf(xn);
  Ab[row * LDIM + d] = f2bf(xn * w[d]);
}

// D = A * B^T, A [M,K] bf16 K-major, B [N,K] bf16 K-major.
// 128x128 tile, 256 threads = 4 waves (2x2), each wave 64x64 via 4x4 grid of
// v_mfma_f32_16x16x32_bf16.
//
// K-loop (ALL modes): LDS-staged via global_load_lds width=16, double-buffered
// (32 KB), ONE barrier per K-step (T3-minimum). Validated round 1.
//
// MODE 0 [GEMM1]: mfma(av,bv); store D fp32 with classic layout
//   (col=l16, row=quad*4+r) [m89/m91 verified].
// MODE 1/2 [GEMM2]: operands SWAPPED -- mfma(bv,av) yields the transposed
//   fragment layout: lane holds D[row = mt*16+l16][col = nt*16+quad*4+r],
//   i.e. 4 contiguous columns of one row per reg quad. Epilogue reads adj as
//   per-lane float4 and stores bf16x4 (8B) straight from accumulators: no LDS
//   transpose, no epilogue barriers. Validated correct round 2 (absmax equal).
//   LDS total ~33 KB -> 4 blocks/CU.
// MODE 1: t = adj*exp(-D) -> bf16 to T; rowsum atomics.
// MODE 2: t = adj*exp(-D) -> fp32 to C; rowsum atomics.
template <int K, int MODE>
__global__ __launch_bounds__(256) void gemm_bt(
    const unsigned short* __restrict__ A,
    const unsigned short* __restrict__ B,
    float* __restrict__ C,
    unsigned short* __restrict__ T,
    const float* __restrict__ adj,
    float* __restrict__ rowsum,
    int ldC) {
  __shared__ alignas(16) char sm[32768];
  __shared__ float rs[2][128];

  const int tid = threadIdx.x;
  const int wave = tid >> 6;
  const int lane = tid & 63;
  const int quad = lane >> 4;
  const int l16 = lane & 15;
  const int wm = wave >> 1;
  const int wn = wave & 1;

  const size_t row0 = (size_t)blockIdx.y * 128;
  const size_t col0 = (size_t)blockIdx.x * 128;

  // staging map: chunk c = wave*128 + lane covers LDS bytes [c*16, c*16+16)
  // within a buffer; tile layout [128 rows][32 k] bf16 => row m = c>>2,
  // k offset = (c&3)*8.
  const int c0 = wave * 128 + lane;
  const int mA = c0 >> 2;
  const int kA = (c0 & 3) * 8;
  const unsigned short* Ag = A + (row0 + mA) * (size_t)K + kA;
  const unsigned short* Bg = B + (col0 + mA) * (size_t)K + kA;
  // double-buffer: buf0 A at sm+0, B at +8192; buf1 A at +16384, B at +24576
  char* const a0d = sm + wave * 2048;
  char* const b0d = sm + 8192 + wave * 2048;
  char* const a1d = sm + 16384 + wave * 2048;
  char* const b1d = sm + 24576 + wave * 2048;

  f32x4 acc[4][4];
#pragma unroll
  for (int i = 0; i < 4; ++i)
#pragma unroll
    for (int j = 0; j < 4; ++j) acc[i][j] = (f32x4)(0.0f);

  auto stage = [&](char* Ad, char* Bd, int k0) {
    async_ld16(Ag + k0, Ad);
    async_ld16(Ag + 16 * (size_t)K + k0, Ad + 1024);  // row m+16, same k off
    async_ld16(Bg + k0, Bd);
    async_ld16(Bg + 16 * (size_t)K + k0, Bd + 1024);
  };
  auto compute = [&](const char* Ab_, const char* Bb_) {
    bf16x8 av[4], bv[4];
#pragma unroll
    for (int mt = 0; mt < 4; ++mt)
      av[mt] = *(const bf16x8*)(Ab_ + (wm * 64 + mt * 16 + l16) * 64 + quad * 16);
#pragma unroll
    for (int nt = 0; nt < 4; ++nt)
      bv[nt] = *(const bf16x8*)(Bb_ + (wn * 64 + nt * 16 + l16) * 64 + quad * 16);
#pragma unroll
    for (int mt = 0; mt < 4; ++mt)
#pragma unroll
      for (int nt = 0; nt < 4; ++nt) {
        if constexpr (MODE == 0)
          acc[mt][nt] = __builtin_amdgcn_mfma_f32_16x16x32_bf16(
              av[mt], bv[nt], acc[mt][nt], 0, 0, 0);
        else
          acc[mt][nt] = __builtin_amdgcn_mfma_f32_16x16x32_bf16(
              bv[nt], av[mt], acc[mt][nt], 0, 0, 0);
      }
  };

  // prologue
  stage(a0d, b0d, 0);
  __syncthreads();
  // steady state: 2 K-steps per trip, one barrier per K-step
  for (int k0 = 0; k0 < K; k0 += 64) {
    if (k0 + 32 < K) stage(a1d, b1d, k0 + 32);   // prefetch overlaps compute
    compute(sm, sm + 8192);
    __syncthreads();
    if (k0 + 64 < K) stage(a0d, b0d, k0 + 64);
    if (k0 + 32 < K) compute(sm + 16384, sm + 24576);
    __syncthreads();
  }

  if constexpr (MODE == 0) {
#pragma unroll
    for (int mt = 0; mt < 4; ++mt)
#pragma unroll
      for (int nt = 0; nt < 4; ++nt)
#pragma unroll
        for (int r = 0; r < 4; ++r) {
          // classic C/D layout: col = l16, row = quad*4 + r [m89/m91]
          size_t gr = row0 + wm * 64 + mt * 16 + quad * 4 + r;
          size_t gc = col0 + wn * 64 + nt * 16 + l16;
          C[gr * (size_t)ldC + gc] = acc[mt][nt][r];
        }
  } else {
    // barrier-free epilogue straight from accumulators (swapped layout)
    float part[4] = {0.0f, 0.0f, 0.0f, 0.0f};
#pragma unroll
    for (int mt = 0; mt < 4; ++mt) {
      const size_t gr = row0 + wm * 64 + mt * 16 + l16;
      const float* arow = adj + gr * NN;
#pragma unroll
      for (int nt = 0; nt < 4; ++nt) {
        const size_t gc = col0 + wn * 64 + nt * 16 + quad * 4;
        float4 a4 = *(const float4*)(arow + gc);
        f32x4 d = acc[mt][nt];
        float t0 = a4.x * __expf(-d[0]);
        float t1 = a4.y * __expf(-d[1]);
        float t2 = a4.z * __expf(-d[2]);
        float t3 = a4.w * __expf(-d[3]);
        if constexpr (MODE == 1) {
          u16x4 p;
          p[0] = (short)f2bf(t0); p[1] = (short)f2bf(t1);
          p[2] = (short)f2bf(t2); p[3] = (short)f2bf(t3);
          // rowsum of the *rounded* t: self-consistent with scale pass
          part[mt] += bf2f(p[0]) + bf2f(p[1]) + bf2f(p[2]) + bf2f(p[3]);
          *(u16x4*)(T + gr * NN + gc) = p;
        } else {
          part[mt] += t0 + t1 + t2 + t3;
          float4 o; o.x = t0; o.y = t1; o.z = t2; o.w = t3;
          *(float4*)(C + gr * NN + gc) = o;
        }
      }
    }
    // reduce across the 4 quads holding the same row (lane bits 4-5)
#pragma unroll
    for (int mt = 0; mt < 4; ++mt) {
      part[mt] += __shfl_xor(part[mt], 16);
      part[mt] += __shfl_xor(part[mt], 32);
    }
    if (quad == 0) {
#pragma unroll
      for (int mt = 0; mt < 4; ++mt)
        rs[wn][wm * 64 + mt * 16 + l16] = part[mt];
    }
    __syncthreads();
    if (tid < 128) atomicAdd(&rowsum[row0 + tid], rs[0][tid] + rs[1][tid]);
  }
}

// out = bf16(t) * (1/rowsum[row]) + 1e-10; 16 elems/thread:
// read 2x short8 (32B), write 4x float4 (64B)
__global__ __launch_bounds__(256) void scale_bf16_kernel(
    const unsigned short* __restrict__ T, const float* __restrict__ rowsum,
    float* __restrict__ out) {
  const size_t i = (size_t)blockIdx.x * 256 + threadIdx.x;  // 16-elem chunk
  const int row = (int)(i >> 9);  // 512 chunks per row
  const float inv = 1.0f / rowsum[row];
  short8 t0 = ((const short8*)T)[i * 2];
  short8 t1 = ((const short8*)T)[i * 2 + 1];
  float4 o0, o1, o2, o3;
  o0.x = bf2f((unsigned short)t0[0]) * inv + 1e-10f;
  o0.y = bf2f((unsigned short)t0[1]) * inv + 1e-10f;
  o0.z = bf2f((unsigned short)t0[2]) * inv + 1e-10f;
  o0.w = bf2f((unsigned short)t0[3]) * inv + 1e-10f;
  o1.x = bf2f((unsigned short)t0[4]) * inv + 1e-10f;
  o1.y = bf2f((unsigned short)t0[5]) * inv + 1e-10f;
  o1.z = bf2f((unsigned short)t0[6]) * inv + 1e-10f;
  o1.w = bf2f((unsigned short)t0[7]) * inv + 1e-10f;
  o2.x = bf2f((unsigned short)t1[0]) * inv + 1e-10f;
  o2.y = bf2f((unsigned short)t1[1]) * inv + 1e-10f;
  o2.z = bf2f((unsigned short)t1[2]) * inv + 1e-10f;
  o2.w = bf2f((unsigned short)t1[3]) * inv + 1e-10f;
  o3.x = bf2f((unsigned short)t1[4]) * inv + 1e-10f;
  o3.y = bf2f((unsigned short)t1[5]) * inv + 1e-10f;
  o3.z = bf2f((unsigned short)t1[6]) * inv + 1e-10f;
  o3.w = bf2f((unsigned short)t1[7]) * inv + 1e-10f;
  float4* dst = (float4*)(out + i * 16);
  dst[0] = o0; dst[1] = o1; dst[2] = o2; dst[3] = o3;
}

// Fallback: in-place out = t / rowsum[row] + 1e-10 (t fp32 already in out)
__global__ __launch_bounds__(256) void scale_f32_kernel(
    float* __restrict__ t, const float* __restrict__ rowsum) {
  const size_t i = (size_t)blockIdx.x * 256 + threadIdx.x;
  const int row = (int)(i >> 11);
  float4 v = ((float4*)t)[i];
  const float inv = 1.0f / rowsum[row];
  v.x = v.x * inv + 1e-10f;
  v.y = v.y * inv + 1e-10f;
  v.z = v.z * inv + 1e-10f;
  v.w = v.w * inv + 1e-10f;
  ((float4*)t)[i] = v;
}

extern "C" void kernel_launch(void* const* d_in, const int* in_sizes, int n_in,
                              void* d_out, int out_size, void* d_ws, size_t ws_size,
                              hipStream_t stream) {
  (void)in_sizes; (void)n_in; (void)out_size;
  const float* x   = (const float*)d_in[0];  // [8192,512]
  const float* adj = (const float*)d_in[1];  // [8192,8192]
  const float* pw  = (const float*)d_in[2];  // [256,512]
  const float* lw  = (const float*)d_in[3];  // [256]
  float* out = (float*)d_out;                // [8192,8192]
  char* ws = (char*)d_ws;

  // ws layout (bytes)
  unsigned short* xb   = (unsigned short*)(ws);              // 8 MB
  unsigned short* pwb  = (unsigned short*)(ws + 8388608);    // 256 KB
  float*          xhat = (float*)(ws + 8650752);             // 8 MB
  unsigned short* Ab   = (unsigned short*)(ws + 17039360);   // 4 MB
  unsigned short* Bb   = (unsigned short*)(ws + 21233664);   // 4 MB
  float*          rsum = (float*)(ws + 25427968);            // 32 KB
  unsigned short* Tbuf = (unsigned short*)(ws + 25460736);   // 128 MB (if fits)
  const bool big_ws = ws_size >= 25460736ull + (size_t)NN * NN * 2ull;

  // 1) cast inputs to bf16 (4 floats/thread)
  cast_kernel<<<(NN * KDIM) / (256 * 4), 256, 0, stream>>>(x, pw, xb, pwb);
  // 2) x_hat = x @ proj_w^T : M=8192, N=256, K=512
  gemm_bt<KDIM, 0><<<dim3(2, 64), 256, 0, stream>>>(xb, pwb, xhat, nullptr, nullptr, nullptr, LDIM);
  // 3) normalize rows; A = xn*w, B = xn (bf16)
  norm_kernel<<<NN, 256, 0, stream>>>(xhat, lw, Ab, Bb);
  // 4) t = adj * exp(-(A@B^T)), plus rowsums
  hipMemsetAsync(rsum, 0, NN * sizeof(float), stream);
  if (big_ws) {
    gemm_bt<LDIM, 1><<<dim3(64, 64), 256, 0, stream>>>(Ab, Bb, nullptr, Tbuf, adj, rsum, NN);
    // 5) out = t / rowsum + eps (16 elems/thread)
    scale_bf16_kernel<<<(NN * NN) / (16 * 256), 256, 0, stream>>>(Tbuf, rsum, out);
  } else {
    gemm_bt<LDIM, 2><<<dim3(64, 64), 256, 0, stream>>>(Ab, Bb, out, nullptr, adj, rsum, NN);
    scale_f32_kernel<<<(NN / 4) * (NN / 256), 256, 0, stream>>>(out, rsum);
  }
}

// Round 4
// 545.544 us; speedup vs baseline: 1.2407x; 1.1028x over previous
//
#include <hip/hip_runtime.h>
#include <stdint.h>

// Problem constants (reference: N=8192, IN_DIM=512, LDIM=256)
#define NN 8192
#define KDIM 512
#define LDIM 256

typedef short bf16x8 __attribute__((ext_vector_type(8)));
typedef short short8 __attribute__((ext_vector_type(8)));
typedef float f32x4 __attribute__((ext_vector_type(4)));
typedef unsigned short u16x4 __attribute__((ext_vector_type(4)));

// fp32 -> bf16 with round-to-nearest-even
__device__ __forceinline__ unsigned short f2bf(float f) {
  unsigned int u = __float_as_uint(f);
  u = (u + 0x7fffu + ((u >> 16) & 1u)) >> 16;
  return (unsigned short)u;
}
__device__ __forceinline__ float bf2f(unsigned short s) {
  return __uint_as_float(((unsigned int)s) << 16);
}

// async global->LDS, 16B per lane; LDS dest = wave-uniform base + lane*16
__device__ __forceinline__ void async_ld16(const unsigned short* g, void* l) {
  __builtin_amdgcn_global_load_lds(
      (const __attribute__((address_space(1))) unsigned int*)g,
      (__attribute__((address_space(3))) unsigned int*)l, 16, 0, 0);
}

// Cast x [8192x512] and proj_w [256x512] to bf16. 4 floats/thread.
__global__ __launch_bounds__(256) void cast_kernel(
    const float* __restrict__ x, const float* __restrict__ pw,
    unsigned short* __restrict__ xb, unsigned short* __restrict__ pwb) {
  const int i = blockIdx.x * 256 + threadIdx.x;  // float4 index
  float4 v = ((const float4*)x)[i];
  u16x4 o;
  o[0] = (short)f2bf(v.x); o[1] = (short)f2bf(v.y);
  o[2] = (short)f2bf(v.z); o[3] = (short)f2bf(v.w);
  ((u16x4*)xb)[i] = o;
  if (i < (LDIM * KDIM) / 4) {
    float4 w = ((const float4*)pw)[i];
    u16x4 ow;
    ow[0] = (short)f2bf(w.x); ow[1] = (short)f2bf(w.y);
    ow[2] = (short)f2bf(w.z); ow[3] = (short)f2bf(w.w);
    ((u16x4*)pwb)[i] = ow;
  }
}

// Fused GEMM1 + row-normalize:
//   x_hat = xb @ pwb^T  (M=8192, N=LDIM=256, K=512), then per-row L2 norm,
//   emit Ab = bf16(xn*w), Bb = bf16(xn). xhat never touches memory.
// BM=32 rows/block (256 blocks = 1/CU), BN=256 = full LDIM so the row norm
// is block-local. 4 waves; wave w computes cols w*64..w*64+63 via
// acc[2][4] of 16x16x32 MFMA (classic layout: col=l16, row=quad*4+r).
__global__ __launch_bounds__(256) void gemm1_norm_kernel(
    const unsigned short* __restrict__ xb,
    const unsigned short* __restrict__ pwb,
    const float* __restrict__ w,
    unsigned short* __restrict__ Ab, unsigned short* __restrict__ Bb) {
  __shared__ alignas(16) unsigned short As[32 * 32];    // 2 KB
  __shared__ alignas(16) unsigned short Bs[256 * 32];   // 16 KB
  __shared__ float nrm[32][5];                          // [row][wave partials + inv]
  __shared__ float wS[LDIM];
  __shared__ alignas(16) unsigned short xnS[32][264];   // bf16 xn tile (pad 8)
  __shared__ alignas(16) unsigned short anS[32][264];   // bf16 xn*w tile

  const int tid = threadIdx.x;
  const int wave = tid >> 6;
  const int lane = tid & 63;
  const int quad = lane >> 4;
  const int l16 = lane & 15;
  const size_t row0 = (size_t)blockIdx.x * 32;

  if (tid < LDIM) wS[tid] = w[tid];

  f32x4 acc[2][4];
#pragma unroll
  for (int i = 0; i < 2; ++i)
#pragma unroll
    for (int j = 0; j < 4; ++j) acc[i][j] = (f32x4)(0.0f);

  // staging maps (chunk = 16B per lane, wave-uniform LDS base):
  // B [256 rows][32 k]: wave w, call j covers LDS bytes (w*4+j)*1024;
  //   lane chunk c=(w*4+j)*64+lane -> row=c>>2, koff=(c&3)*8
  // A [32 rows][32 k]: wave 0 only, 2 calls j2: c=j2*64+lane
  for (int k0 = 0; k0 < KDIM; k0 += 32) {
#pragma unroll
    for (int j = 0; j < 4; ++j) {
      const int c = (wave * 4 + j) * 64 + lane;
      async_ld16(pwb + (size_t)(c >> 2) * KDIM + (c & 3) * 8 + k0,
                 (char*)Bs + (wave * 4 + j) * 1024);
    }
    if (wave == 0) {
#pragma unroll
      for (int j2 = 0; j2 < 2; ++j2) {
        const int c = j2 * 64 + lane;
        async_ld16(xb + (row0 + (c >> 2)) * (size_t)KDIM + (c & 3) * 8 + k0,
                   (char*)As + j2 * 1024);
      }
    }
    __syncthreads();  // drain staging
    bf16x8 av[2], bv[4];
#pragma unroll
    for (int mt = 0; mt < 2; ++mt)
      av[mt] = *(const bf16x8*)(As + (mt * 16 + l16) * 32 + quad * 8);
#pragma unroll
    for (int nt = 0; nt < 4; ++nt)
      bv[nt] = *(const bf16x8*)(Bs + (wave * 64 + nt * 16 + l16) * 32 + quad * 8);
#pragma unroll
    for (int mt = 0; mt < 2; ++mt)
#pragma unroll
      for (int nt = 0; nt < 4; ++nt)
        acc[mt][nt] = __builtin_amdgcn_mfma_f32_16x16x32_bf16(
            av[mt], bv[nt], acc[mt][nt], 0, 0, 0);
    __syncthreads();  // LDS reads done before restage
  }

  // per-(row,wave) sum of squares: lane holds rows 16*mt+quad*4+r,
  // cols l16+16*nt+64*wave. Reduce over l16 (16 lanes, same quad).
#pragma unroll
  for (int mt = 0; mt < 2; ++mt)
#pragma unroll
    for (int r = 0; r < 4; ++r) {
      float s = 0.0f;
#pragma unroll
      for (int nt = 0; nt < 4; ++nt) s += acc[mt][nt][r] * acc[mt][nt][r];
      s += __shfl_xor(s, 1);
      s += __shfl_xor(s, 2);
      s += __shfl_xor(s, 4);
      s += __shfl_xor(s, 8);
      if (l16 == 0) nrm[mt * 16 + quad * 4 + r][wave] = s;
    }
  __syncthreads();
  if (tid < 32)
    nrm[tid][4] = rsqrtf(nrm[tid][0] + nrm[tid][1] + nrm[tid][2] + nrm[tid][3]);
  __syncthreads();

  // scale from full-precision accumulators; stage bf16 tiles in LDS
#pragma unroll
  for (int mt = 0; mt < 2; ++mt)
#pragma unroll
    for (int r = 0; r < 4; ++r) {
      const int row = mt * 16 + quad * 4 + r;
      const float inv = nrm[row][4];
#pragma unroll
      for (int nt = 0; nt < 4; ++nt) {
        const int col = wave * 64 + nt * 16 + l16;
        const float xn = acc[mt][nt][r] * inv;
        xnS[row][col] = f2bf(xn);
        anS[row][col] = f2bf(xn * wS[col]);
      }
    }
  __syncthreads();

  // repack-store: thread t -> row t>>3, cols (t&7)*32..+32 (4x 16B each)
  {
    const int row = tid >> 3;
    const int cb = (tid & 7) * 32;
    unsigned short* bdst = Bb + (row0 + row) * LDIM + cb;
    unsigned short* adst = Ab + (row0 + row) * LDIM + cb;
#pragma unroll
    for (int q = 0; q < 4; ++q) {
      ((short8*)bdst)[q] = *(const short8*)&xnS[row][cb + q * 8];
      ((short8*)adst)[q] = *(const short8*)&anS[row][cb + q * 8];
    }
  }
}

// GEMM2: D = A * B^T (A=xn*w, B=xn, [8192,256] bf16 K-major), then
// t = adj*exp(-D) with rowsums. RESTORED round-0 structure verbatim
// (serial global_load_lds staging, 2 barriers/K-step, slab-LDS-transpose
// epilogue) -- the empirically fastest variant (~110 us) -- plus ONE
// addition: bijective XCD-aware block swizzle (4096 blocks % 8 == 0) so
// the 64 blocks sharing an A-panel land on one XCD's L2.
// MODE 1: t -> bf16 T + rowsum atomics.   MODE 2: t -> fp32 C + rowsums.
template <int K, int MODE>
__global__ __launch_bounds__(256) void gemm_bt(
    const unsigned short* __restrict__ A,
    const unsigned short* __restrict__ B,
    float* __restrict__ C,
    unsigned short* __restrict__ T,
    const float* __restrict__ adj,
    float* __restrict__ rowsum) {
  __shared__ unsigned short As[128 * 32];
  __shared__ unsigned short Bs[128 * 32];
  __shared__ float rs[128];
  __shared__ float trans[32 * 132];

  const int tid = threadIdx.x;
  const int wave = tid >> 6;
  const int lane = tid & 63;
  const int quad = lane >> 4;
  const int l16 = lane & 15;
  const int wm = wave >> 1;
  const int wn = wave & 1;

  // XCD swizzle: lin -> (xcd band of 8 consecutive y-tiles, x sweeps fastest)
  const int lin = blockIdx.y * 64 + blockIdx.x;
  const int swz = (lin & 7) * 512 + (lin >> 3);
  const size_t row0 = (size_t)(swz >> 6) * 128;
  const size_t col0 = (size_t)(swz & 63) * 128;

  // staging map: chunk c = wave*128 + lane covers LDS bytes [c*16, c*16+16)
  // tile layout [128 rows][32 k] bf16 => row m = c>>2, k offset = (c&3)*8
  const int c0 = wave * 128 + lane;
  const int mA = c0 >> 2;
  const int kA = (c0 & 3) * 8;
  const unsigned short* Ag = A + (row0 + mA) * (size_t)K + kA;
  const unsigned short* Bg = B + (col0 + mA) * (size_t)K + kA;
  char* AsB = (char*)As;
  char* BsB = (char*)Bs;
  unsigned short* dA0 = (unsigned short*)(AsB + wave * 2048);
  unsigned short* dA1 = (unsigned short*)(AsB + wave * 2048 + 1024);
  unsigned short* dB0 = (unsigned short*)(BsB + wave * 2048);
  unsigned short* dB1 = (unsigned short*)(BsB + wave * 2048 + 1024);

  f32x4 acc[4][4];
#pragma unroll
  for (int i = 0; i < 4; ++i)
#pragma unroll
    for (int j = 0; j < 4; ++j) acc[i][j] = (f32x4)(0.0f);

  for (int k0 = 0; k0 < K; k0 += 32) {
    async_ld16(Ag + k0, dA0);
    async_ld16(Ag + 16 * (size_t)K + k0, dA1);  // row m+16, same k offset
    async_ld16(Bg + k0, dB0);
    async_ld16(Bg + 16 * (size_t)K + k0, dB1);
    __syncthreads();  // drains vmcnt: staging complete

    bf16x8 av[4], bv[4];
#pragma unroll
    for (int mt = 0; mt < 4; ++mt)
      av[mt] = *(const bf16x8*)(AsB + (wm * 64 + mt * 16 + l16) * 64 + quad * 16);
#pragma unroll
    for (int nt = 0; nt < 4; ++nt)
      bv[nt] = *(const bf16x8*)(BsB + (wn * 64 + nt * 16 + l16) * 64 + quad * 16);
#pragma unroll
    for (int mt = 0; mt < 4; ++mt)
#pragma unroll
      for (int nt = 0; nt < 4; ++nt)
        acc[mt][nt] = __builtin_amdgcn_mfma_f32_16x16x32_bf16(av[mt], bv[nt], acc[mt][nt], 0, 0, 0);
    __syncthreads();  // all waves done reading LDS before next stage
  }

  // 32x128 slab transpose; stride 132 keeps write conflicts 2-way (free)
  const int s = tid >> 3;   // 0..31: slab-local row this thread consumes
  const int cb = tid & 7;   // 8 threads/row, 16 cols each
  const int coff = cb * 16;
#pragma unroll
  for (int mt = 0; mt < 4; ++mt) {
    __syncthreads();  // prior slab's reads done before overwrite
#pragma unroll
    for (int nt = 0; nt < 4; ++nt)
#pragma unroll
      for (int r = 0; r < 4; ++r)
        trans[(wm * 16 + quad * 4 + r) * 132 + wn * 64 + nt * 16 + l16] =
            acc[mt][nt][r];
    __syncthreads();
    // slab row s -> global row
    const size_t gr = row0 + (size_t)(s >> 4) * 64 + mt * 16 + (s & 15);
    const float* arow = adj + gr * NN + col0 + coff;
    float av16[16];
#pragma unroll
    for (int q = 0; q < 4; ++q) {
      float4 a4 = ((const float4*)arow)[q];
      av16[q * 4 + 0] = a4.x;
      av16[q * 4 + 1] = a4.y;
      av16[q * 4 + 2] = a4.z;
      av16[q * 4 + 3] = a4.w;
    }
    const float* drow = &trans[s * 132 + coff];
    float part = 0.0f;
    if constexpr (MODE == 1) {
      short8 p0, p1;
#pragma unroll
      for (int j = 0; j < 16; ++j) {
        float tv = av16[j] * __expf(-drow[j]);
        unsigned short us = f2bf(tv);
        part += bf2f(us);  // rowsum of the *rounded* t: self-consistent
        if (j < 8) p0[j] = (short)us; else p1[j - 8] = (short)us;
      }
      short8* trow = (short8*)(T + gr * NN + col0 + coff);
      trow[0] = p0;
      trow[1] = p1;
    } else {
      float4 o[4];
#pragma unroll
      for (int j = 0; j < 16; ++j) {
        float tv = av16[j] * __expf(-drow[j]);
        part += tv;
        ((float*)o)[j] = tv;
      }
      float4* crow = (float4*)(C + gr * NN + col0 + coff);
#pragma unroll
      for (int q = 0; q < 4; ++q) crow[q] = o[q];
    }
    // reduce the 8 threads sharing this row (lanes s*8..s*8+7)
    part += __shfl_xor(part, 1);
    part += __shfl_xor(part, 2);
    part += __shfl_xor(part, 4);
    if (cb == 0) rs[(s >> 4) * 64 + mt * 16 + (s & 15)] = part;  // unique owner
  }
  __syncthreads();
  if (tid < 128) atomicAdd(&rowsum[row0 + tid], rs[tid]);
}

// out = bf16(t) * (1/rowsum[row]) + 1e-10; read ushort8, write 2x float4
// (round-0 proven variant)
__global__ __launch_bounds__(256) void scale_bf16_kernel(
    const unsigned short* __restrict__ T, const float* __restrict__ rowsum,
    float* __restrict__ out) {
  const size_t i = (size_t)blockIdx.x * 256 + threadIdx.x;  // short8 index
  const int row = (int)(i >> 10);  // 1024 short8 per row
  short8 tv = ((const short8*)T)[i];
  const float inv = 1.0f / rowsum[row];
  float4 o0, o1;
  o0.x = bf2f((unsigned short)tv[0]) * inv + 1e-10f;
  o0.y = bf2f((unsigned short)tv[1]) * inv + 1e-10f;
  o0.z = bf2f((unsigned short)tv[2]) * inv + 1e-10f;
  o0.w = bf2f((unsigned short)tv[3]) * inv + 1e-10f;
  o1.x = bf2f((unsigned short)tv[4]) * inv + 1e-10f;
  o1.y = bf2f((unsigned short)tv[5]) * inv + 1e-10f;
  o1.z = bf2f((unsigned short)tv[6]) * inv + 1e-10f;
  o1.w = bf2f((unsigned short)tv[7]) * inv + 1e-10f;
  ((float4*)out)[i * 2] = o0;
  ((float4*)out)[i * 2 + 1] = o1;
}

// Fallback: in-place out = t / rowsum[row] + 1e-10 (t fp32 already in out)
__global__ __launch_bounds__(256) void scale_f32_kernel(
    float* __restrict__ t, const float* __restrict__ rowsum) {
  const size_t i = (size_t)blockIdx.x * 256 + threadIdx.x;
  const int row = (int)(i >> 11);
  float4 v = ((float4*)t)[i];
  const float inv = 1.0f / rowsum[row];
  v.x = v.x * inv + 1e-10f;
  v.y = v.y * inv + 1e-10f;
  v.z = v.z * inv + 1e-10f;
  v.w = v.w * inv + 1e-10f;
  ((float4*)t)[i] = v;
}

extern "C" void kernel_launch(void* const* d_in, const int* in_sizes, int n_in,
                              void* d_out, int out_size, void* d_ws, size_t ws_size,
                              hipStream_t stream) {
  (void)in_sizes; (void)n_in; (void)out_size;
  const float* x   = (const float*)d_in[0];  // [8192,512]
  const float* adj = (const float*)d_in[1];  // [8192,8192]
  const float* pw  = (const float*)d_in[2];  // [256,512]
  const float* lw  = (const float*)d_in[3];  // [256]
  float* out = (float*)d_out;                // [8192,8192]
  char* ws = (char*)d_ws;

  // ws layout (bytes) -- unchanged offsets (xhat hole now unused)
  unsigned short* xb   = (unsigned short*)(ws);              // 8 MB
  unsigned short* pwb  = (unsigned short*)(ws + 8388608);    // 256 KB
  unsigned short* Ab   = (unsigned short*)(ws + 17039360);   // 4 MB
  unsigned short* Bb   = (unsigned short*)(ws + 21233664);   // 4 MB
  float*          rsum = (float*)(ws + 25427968);            // 32 KB
  unsigned short* Tbuf = (unsigned short*)(ws + 25460736);   // 128 MB (if fits)
  const bool big_ws = ws_size >= 25460736ull + (size_t)NN * NN * 2ull;

  // 1) cast inputs to bf16 (4 floats/thread)
  cast_kernel<<<(NN * KDIM) / (256 * 4), 256, 0, stream>>>(x, pw, xb, pwb);
  // 2+3) fused: x_hat = x @ proj_w^T, row-normalize, emit A=xn*w, B=xn (bf16)
  gemm1_norm_kernel<<<NN / 32, 256, 0, stream>>>(xb, pwb, lw, Ab, Bb);
  // 4) t = adj * exp(-(A@B^T)), plus rowsums
  hipMemsetAsync(rsum, 0, NN * sizeof(float), stream);
  if (big_ws) {
    gemm_bt<LDIM, 1><<<dim3(64, 64), 256, 0, stream>>>(Ab, Bb, nullptr, Tbuf, adj, rsum);
    // 5) out = t / rowsum + eps
    scale_bf16_kernel<<<(NN / 8) * (NN / 256), 256, 0, stream>>>(Tbuf, rsum, out);
  } else {
    gemm_bt<LDIM, 2><<<dim3(64, 64), 256, 0, stream>>>(Ab, Bb, out, nullptr, adj, rsum);
    scale_f32_kernel<<<(NN / 4) * (NN / 256), 256, 0, stream>>>(out, rsum);
  }
}

// Round 5
// 545.394 us; speedup vs baseline: 1.2410x; 1.0003x over previous
//
#include <hip/hip_runtime.h>
#include <stdint.h>

// Problem constants (reference: N=8192, IN_DIM=512, LDIM=256)
#define NN 8192
#define KDIM 512
#define LDIM 256

typedef short bf16x8 __attribute__((ext_vector_type(8)));
typedef short short8 __attribute__((ext_vector_type(8)));
typedef float f32x4 __attribute__((ext_vector_type(4)));
typedef unsigned short u16x4 __attribute__((ext_vector_type(4)));

// fp32 -> bf16 with round-to-nearest-even
__device__ __forceinline__ unsigned short f2bf(float f) {
  unsigned int u = __float_as_uint(f);
  u = (u + 0x7fffu + ((u >> 16) & 1u)) >> 16;
  return (unsigned short)u;
}
__device__ __forceinline__ float bf2f(unsigned short s) {
  return __uint_as_float(((unsigned int)s) << 16);
}

// async global->LDS, 16B per lane; LDS dest = wave-uniform base + lane*16
__device__ __forceinline__ void async_ld16(const unsigned short* g, void* l) {
  __builtin_amdgcn_global_load_lds(
      (const __attribute__((address_space(1))) unsigned int*)g,
      (__attribute__((address_space(3))) unsigned int*)l, 16, 0, 0);
}

// Cast x [8192x512] and proj_w [256x512] to bf16. 4 floats/thread.
__global__ __launch_bounds__(256) void cast_kernel(
    const float* __restrict__ x, const float* __restrict__ pw,
    unsigned short* __restrict__ xb, unsigned short* __restrict__ pwb) {
  const int i = blockIdx.x * 256 + threadIdx.x;  // float4 index
  float4 v = ((const float4*)x)[i];
  u16x4 o;
  o[0] = (short)f2bf(v.x); o[1] = (short)f2bf(v.y);
  o[2] = (short)f2bf(v.z); o[3] = (short)f2bf(v.w);
  ((u16x4*)xb)[i] = o;
  if (i < (LDIM * KDIM) / 4) {
    float4 w = ((const float4*)pw)[i];
    u16x4 ow;
    ow[0] = (short)f2bf(w.x); ow[1] = (short)f2bf(w.y);
    ow[2] = (short)f2bf(w.z); ow[3] = (short)f2bf(w.w);
    ((u16x4*)pwb)[i] = ow;
  }
}

// Fused GEMM1 + row-normalize (validated round 4):
//   x_hat = xb @ pwb^T  (M=8192, N=LDIM=256, K=512), then per-row L2 norm,
//   emit Ab = bf16(xn*w), Bb = bf16(xn). xhat never touches memory.
__global__ __launch_bounds__(256) void gemm1_norm_kernel(
    const unsigned short* __restrict__ xb,
    const unsigned short* __restrict__ pwb,
    const float* __restrict__ w,
    unsigned short* __restrict__ Ab, unsigned short* __restrict__ Bb) {
  __shared__ alignas(16) unsigned short As[32 * 32];    // 2 KB
  __shared__ alignas(16) unsigned short Bs[256 * 32];   // 16 KB
  __shared__ float nrm[32][5];                          // [row][wave partials + inv]
  __shared__ float wS[LDIM];
  __shared__ alignas(16) unsigned short xnS[32][264];   // bf16 xn tile (pad 8)
  __shared__ alignas(16) unsigned short anS[32][264];   // bf16 xn*w tile

  const int tid = threadIdx.x;
  const int wave = tid >> 6;
  const int lane = tid & 63;
  const int quad = lane >> 4;
  const int l16 = lane & 15;
  const size_t row0 = (size_t)blockIdx.x * 32;

  if (tid < LDIM) wS[tid] = w[tid];

  f32x4 acc[2][4];
#pragma unroll
  for (int i = 0; i < 2; ++i)
#pragma unroll
    for (int j = 0; j < 4; ++j) acc[i][j] = (f32x4)(0.0f);

  for (int k0 = 0; k0 < KDIM; k0 += 32) {
#pragma unroll
    for (int j = 0; j < 4; ++j) {
      const int c = (wave * 4 + j) * 64 + lane;
      async_ld16(pwb + (size_t)(c >> 2) * KDIM + (c & 3) * 8 + k0,
                 (char*)Bs + (wave * 4 + j) * 1024);
    }
    if (wave == 0) {
#pragma unroll
      for (int j2 = 0; j2 < 2; ++j2) {
        const int c = j2 * 64 + lane;
        async_ld16(xb + (row0 + (c >> 2)) * (size_t)KDIM + (c & 3) * 8 + k0,
                   (char*)As + j2 * 1024);
      }
    }
    __syncthreads();  // drain staging
    bf16x8 av[2], bv[4];
#pragma unroll
    for (int mt = 0; mt < 2; ++mt)
      av[mt] = *(const bf16x8*)(As + (mt * 16 + l16) * 32 + quad * 8);
#pragma unroll
    for (int nt = 0; nt < 4; ++nt)
      bv[nt] = *(const bf16x8*)(Bs + (wave * 64 + nt * 16 + l16) * 32 + quad * 8);
#pragma unroll
    for (int mt = 0; mt < 2; ++mt)
#pragma unroll
      for (int nt = 0; nt < 4; ++nt)
        acc[mt][nt] = __builtin_amdgcn_mfma_f32_16x16x32_bf16(
            av[mt], bv[nt], acc[mt][nt], 0, 0, 0);
    __syncthreads();  // LDS reads done before restage
  }

  // per-(row,wave) sum of squares: lane holds rows 16*mt+quad*4+r,
  // cols l16+16*nt+64*wave. Reduce over l16 (16 lanes, same quad).
#pragma unroll
  for (int mt = 0; mt < 2; ++mt)
#pragma unroll
    for (int r = 0; r < 4; ++r) {
      float s = 0.0f;
#pragma unroll
      for (int nt = 0; nt < 4; ++nt) s += acc[mt][nt][r] * acc[mt][nt][r];
      s += __shfl_xor(s, 1);
      s += __shfl_xor(s, 2);
      s += __shfl_xor(s, 4);
      s += __shfl_xor(s, 8);
      if (l16 == 0) nrm[mt * 16 + quad * 4 + r][wave] = s;
    }
  __syncthreads();
  if (tid < 32)
    nrm[tid][4] = rsqrtf(nrm[tid][0] + nrm[tid][1] + nrm[tid][2] + nrm[tid][3]);
  __syncthreads();

  // scale from full-precision accumulators; stage bf16 tiles in LDS
#pragma unroll
  for (int mt = 0; mt < 2; ++mt)
#pragma unroll
    for (int r = 0; r < 4; ++r) {
      const int row = mt * 16 + quad * 4 + r;
      const float inv = nrm[row][4];
#pragma unroll
      for (int nt = 0; nt < 4; ++nt) {
        const int col = wave * 64 + nt * 16 + l16;
        const float xn = acc[mt][nt][r] * inv;
        xnS[row][col] = f2bf(xn);
        anS[row][col] = f2bf(xn * wS[col]);
      }
    }
  __syncthreads();

  // repack-store: thread t -> row t>>3, cols (t&7)*32..+32 (4x 16B each)
  {
    const int row = tid >> 3;
    const int cb = (tid & 7) * 32;
    unsigned short* bdst = Bb + (row0 + row) * LDIM + cb;
    unsigned short* adst = Ab + (row0 + row) * LDIM + cb;
#pragma unroll
    for (int q = 0; q < 4; ++q) {
      ((short8*)bdst)[q] = *(const short8*)&xnS[row][cb + q * 8];
      ((short8*)adst)[q] = *(const short8*)&anS[row][cb + q * 8];
    }
  }
}

// GEMM2: D = A * B^T (A=xn*w, B=xn, [8192,256] bf16 K-major), then
// t = adj*exp(-D) with rowsums. Round-0 proven structure (serial
// global_load_lds staging, 2 barriers/K-step, slab-LDS-transpose epilogue)
// + XCD swizzle (r4) + NEW: T14 adj register-prefetch pipeline:
//   - slab 0's adj (4x float4/thread) issued inside the LAST K-iteration,
//     draining at the same barrier as the A/B staging (latency overlapped);
//   - slab mt+1's adj issued right after slab mt's values are consumed,
//     flying under exp/pack/store + the next slab's barriers/trans-writes.
// Traffic identical; +16 VGPR; LDS unchanged (33.9 KB -> 4 blocks/CU).
// MODE 1: t -> bf16 T + rowsum atomics.   MODE 2: t -> fp32 C + rowsums.
template <int K, int MODE>
__global__ __launch_bounds__(256) void gemm_bt(
    const unsigned short* __restrict__ A,
    const unsigned short* __restrict__ B,
    float* __restrict__ C,
    unsigned short* __restrict__ T,
    const float* __restrict__ adj,
    float* __restrict__ rowsum) {
  __shared__ unsigned short As[128 * 32];
  __shared__ unsigned short Bs[128 * 32];
  __shared__ float rs[128];
  __shared__ float trans[32 * 132];

  const int tid = threadIdx.x;
  const int wave = tid >> 6;
  const int lane = tid & 63;
  const int quad = lane >> 4;
  const int l16 = lane & 15;
  const int wm = wave >> 1;
  const int wn = wave & 1;

  // XCD swizzle: lin -> (xcd band of 8 consecutive y-tiles, x sweeps fastest)
  const int lin = blockIdx.y * 64 + blockIdx.x;
  const int swz = (lin & 7) * 512 + (lin >> 3);
  const size_t row0 = (size_t)(swz >> 6) * 128;
  const size_t col0 = (size_t)(swz & 63) * 128;

  // staging map: chunk c = wave*128 + lane covers LDS bytes [c*16, c*16+16)
  // tile layout [128 rows][32 k] bf16 => row m = c>>2, k offset = (c&3)*8
  const int c0 = wave * 128 + lane;
  const int mA = c0 >> 2;
  const int kA = (c0 & 3) * 8;
  const unsigned short* Ag = A + (row0 + mA) * (size_t)K + kA;
  const unsigned short* Bg = B + (col0 + mA) * (size_t)K + kA;
  char* AsB = (char*)As;
  char* BsB = (char*)Bs;
  unsigned short* dA0 = (unsigned short*)(AsB + wave * 2048);
  unsigned short* dA1 = (unsigned short*)(AsB + wave * 2048 + 1024);
  unsigned short* dB0 = (unsigned short*)(BsB + wave * 2048);
  unsigned short* dB1 = (unsigned short*)(BsB + wave * 2048 + 1024);

  // epilogue geometry (also used by the in-K-loop adj prefetch)
  const int s = tid >> 3;   // 0..31: slab-local row this thread consumes
  const int cb = tid & 7;   // 8 threads/row, 16 cols each
  const int coff = cb * 16;
  const size_t grB = row0 + (size_t)(s >> 4) * 64 + (s & 15);  // + mt*16
  const float* aBase = (MODE != 0) ? (adj + col0 + coff) : nullptr;
  float4 pf[4];  // in-flight adj prefetch for the next slab

  f32x4 acc[4][4];
#pragma unroll
  for (int i = 0; i < 4; ++i)
#pragma unroll
    for (int j = 0; j < 4; ++j) acc[i][j] = (f32x4)(0.0f);

  for (int k0 = 0; k0 < K; k0 += 32) {
    async_ld16(Ag + k0, dA0);
    async_ld16(Ag + 16 * (size_t)K + k0, dA1);  // row m+16, same k offset
    async_ld16(Bg + k0, dB0);
    async_ld16(Bg + 16 * (size_t)K + k0, dB1);
    if constexpr (MODE != 0) {
      if (k0 + 32 >= K) {
        // prefetch slab 0's adj; drains at the same barrier as staging
        const float* arow = aBase + grB * NN;
#pragma unroll
        for (int q = 0; q < 4; ++q) pf[q] = ((const float4*)arow)[q];
      }
    }
    __syncthreads();  // drains vmcnt: staging (and last-iter prefetch) done

    bf16x8 av[4], bv[4];
#pragma unroll
    for (int mt = 0; mt < 4; ++mt)
      av[mt] = *(const bf16x8*)(AsB + (wm * 64 + mt * 16 + l16) * 64 + quad * 16);
#pragma unroll
    for (int nt = 0; nt < 4; ++nt)
      bv[nt] = *(const bf16x8*)(BsB + (wn * 64 + nt * 16 + l16) * 64 + quad * 16);
#pragma unroll
    for (int mt = 0; mt < 4; ++mt)
#pragma unroll
      for (int nt = 0; nt < 4; ++nt)
        acc[mt][nt] = __builtin_amdgcn_mfma_f32_16x16x32_bf16(av[mt], bv[nt], acc[mt][nt], 0, 0, 0);
    __syncthreads();  // all waves done reading LDS before next stage
  }

  if constexpr (MODE == 0) {
#pragma unroll
    for (int mt = 0; mt < 4; ++mt)
#pragma unroll
      for (int nt = 0; nt < 4; ++nt)
#pragma unroll
        for (int r = 0; r < 4; ++r) {
          // classic C/D layout: col = l16, row = quad*4 + r [m89/m91]
          size_t gr = row0 + wm * 64 + mt * 16 + quad * 4 + r;
          size_t gc = col0 + wn * 64 + nt * 16 + l16;
          C[gr * (size_t)LDIM + gc] = acc[mt][nt][r];
        }
  } else {
    // 32x128 slab transpose; stride 132 keeps write conflicts 2-way (free)
#pragma unroll
    for (int mt = 0; mt < 4; ++mt) {
      __syncthreads();  // prior slab's reads done before overwrite
#pragma unroll
      for (int nt = 0; nt < 4; ++nt)
#pragma unroll
        for (int r = 0; r < 4; ++r)
          trans[(wm * 16 + quad * 4 + r) * 132 + wn * 64 + nt * 16 + l16] =
              acc[mt][nt][r];
      __syncthreads();
      // consume the prefetched adj for this slab
      float av16[16];
#pragma unroll
      for (int q = 0; q < 4; ++q) {
        av16[q * 4 + 0] = pf[q].x;
        av16[q * 4 + 1] = pf[q].y;
        av16[q * 4 + 2] = pf[q].z;
        av16[q * 4 + 3] = pf[q].w;
      }
      // issue next slab's adj; hides under exp/pack/store + next barriers
      if (mt < 3) {
        const float* arow = aBase + (grB + (size_t)(mt + 1) * 16) * NN;
#pragma unroll
        for (int q = 0; q < 4; ++q) pf[q] = ((const float4*)arow)[q];
      }
      const size_t gr = grB + (size_t)mt * 16;
      const float* drow = &trans[s * 132 + coff];
      float part = 0.0f;
      if constexpr (MODE == 1) {
        short8 p0, p1;
#pragma unroll
        for (int j = 0; j < 16; ++j) {
          float tv = av16[j] * __expf(-drow[j]);
          unsigned short us = f2bf(tv);
          part += bf2f(us);  // rowsum of the *rounded* t: self-consistent
          if (j < 8) p0[j] = (short)us; else p1[j - 8] = (short)us;
        }
        short8* trow = (short8*)(T + gr * NN + col0 + coff);
        trow[0] = p0;
        trow[1] = p1;
      } else {
        float4 o[4];
#pragma unroll
        for (int j = 0; j < 16; ++j) {
          float tv = av16[j] * __expf(-drow[j]);
          part += tv;
          ((float*)o)[j] = tv;
        }
        float4* crow = (float4*)(C + gr * NN + col0 + coff);
#pragma unroll
        for (int q = 0; q < 4; ++q) crow[q] = o[q];
      }
      // reduce the 8 threads sharing this row (lanes s*8..s*8+7)
      part += __shfl_xor(part, 1);
      part += __shfl_xor(part, 2);
      part += __shfl_xor(part, 4);
      if (cb == 0) rs[(s >> 4) * 64 + mt * 16 + (s & 15)] = part;  // unique owner
    }
    __syncthreads();
    if (tid < 128) atomicAdd(&rowsum[row0 + tid], rs[tid]);
  }
}

// out = bf16(t) * (1/rowsum[row]) + 1e-10; read ushort8, write 2x float4
// (round-0 proven variant)
__global__ __launch_bounds__(256) void scale_bf16_kernel(
    const unsigned short* __restrict__ T, const float* __restrict__ rowsum,
    float* __restrict__ out) {
  const size_t i = (size_t)blockIdx.x * 256 + threadIdx.x;  // short8 index
  const int row = (int)(i >> 10);  // 1024 short8 per row
  short8 tv = ((const short8*)T)[i];
  const float inv = 1.0f / rowsum[row];
  float4 o0, o1;
  o0.x = bf2f((unsigned short)tv[0]) * inv + 1e-10f;
  o0.y = bf2f((unsigned short)tv[1]) * inv + 1e-10f;
  o0.z = bf2f((unsigned short)tv[2]) * inv + 1e-10f;
  o0.w = bf2f((unsigned short)tv[3]) * inv + 1e-10f;
  o1.x = bf2f((unsigned short)tv[4]) * inv + 1e-10f;
  o1.y = bf2f((unsigned short)tv[5]) * inv + 1e-10f;
  o1.z = bf2f((unsigned short)tv[6]) * inv + 1e-10f;
  o1.w = bf2f((unsigned short)tv[7]) * inv + 1e-10f;
  ((float4*)out)[i * 2] = o0;
  ((float4*)out)[i * 2 + 1] = o1;
}

// Fallback: in-place out = t / rowsum[row] + 1e-10 (t fp32 already in out)
__global__ __launch_bounds__(256) void scale_f32_kernel(
    float* __restrict__ t, const float* __restrict__ rowsum) {
  const size_t i = (size_t)blockIdx.x * 256 + threadIdx.x;
  const int row = (int)(i >> 11);
  float4 v = ((float4*)t)[i];
  const float inv = 1.0f / rowsum[row];
  v.x = v.x * inv + 1e-10f;
  v.y = v.y * inv + 1e-10f;
  v.z = v.z * inv + 1e-10f;
  v.w = v.w * inv + 1e-10f;
  ((float4*)t)[i] = v;
}

extern "C" void kernel_launch(void* const* d_in, const int* in_sizes, int n_in,
                              void* d_out, int out_size, void* d_ws, size_t ws_size,
                              hipStream_t stream) {
  (void)in_sizes; (void)n_in; (void)out_size;
  const float* x   = (const float*)d_in[0];  // [8192,512]
  const float* adj = (const float*)d_in[1];  // [8192,8192]
  const float* pw  = (const float*)d_in[2];  // [256,512]
  const float* lw  = (const float*)d_in[3];  // [256]
  float* out = (float*)d_out;                // [8192,8192]
  char* ws = (char*)d_ws;

  // ws layout (bytes) -- unchanged offsets (xhat hole now unused)
  unsigned short* xb   = (unsigned short*)(ws);              // 8 MB
  unsigned short* pwb  = (unsigned short*)(ws + 8388608);    // 256 KB
  unsigned short* Ab   = (unsigned short*)(ws + 17039360);   // 4 MB
  unsigned short* Bb   = (unsigned short*)(ws + 21233664);   // 4 MB
  float*          rsum = (float*)(ws + 25427968);            // 32 KB
  unsigned short* Tbuf = (unsigned short*)(ws + 25460736);   // 128 MB (if fits)
  const bool big_ws = ws_size >= 25460736ull + (size_t)NN * NN * 2ull;

  // 1) cast inputs to bf16 (4 floats/thread)
  cast_kernel<<<(NN * KDIM) / (256 * 4), 256, 0, stream>>>(x, pw, xb, pwb);
  // 2+3) fused: x_hat = x @ proj_w^T, row-normalize, emit A=xn*w, B=xn (bf16)
  gemm1_norm_kernel<<<NN / 32, 256, 0, stream>>>(xb, pwb, lw, Ab, Bb);
  // 4) t = adj * exp(-(A@B^T)), plus rowsums
  hipMemsetAsync(rsum, 0, NN * sizeof(float), stream);
  if (big_ws) {
    gemm_bt<LDIM, 1><<<dim3(64, 64), 256, 0, stream>>>(Ab, Bb, nullptr, Tbuf, adj, rsum);
    // 5) out = t / rowsum + eps
    scale_bf16_kernel<<<(NN / 8) * (NN / 256), 256, 0, stream>>>(Tbuf, rsum, out);
  } else {
    gemm_bt<LDIM, 2><<<dim3(64, 64), 256, 0, stream>>>(Ab, Bb, out, nullptr, adj, rsum);
    scale_f32_kernel<<<(NN / 4) * (NN / 256), 256, 0, stream>>>(out, rsum);
  }
}